// Round 2
// baseline (348.888 us; speedup 1.0000x reference)
//
#include <hip/hip_runtime.h>
#include <hip/hip_bf16.h>

typedef _Float16 f16;
typedef __attribute__((ext_vector_type(8))) _Float16 f16x8;
typedef __attribute__((ext_vector_type(4))) float f32x4;

#define CD 256
#define ND 4096
#define GD 32

// ============================================================================
// Kernel 1: QKV projection.  q[b,o,n] = sum_c W[o,c] x[b,c,n] + bias[o]
// Q,K written TRANSPOSED [b][n][c] f16 (so attention fragments are contiguous);
// V written natural [b][c][n] f16.
// GEMM tile: 64(o) x 64(n), BK=32, 4 waves each 32x32.
// ============================================================================
__global__ __launch_bounds__(256)
void k_proj_qkv(const float* __restrict__ x,
                const float* __restrict__ Wq, const float* __restrict__ bq,
                const float* __restrict__ Wk, const float* __restrict__ bk,
                const float* __restrict__ Wv, const float* __restrict__ bv,
                f16* __restrict__ Qt, f16* __restrict__ Kt, f16* __restrict__ Vb)
{
    __shared__ f16 As[64][40];   // [o][k]
    __shared__ f16 Bs[64][40];   // [n][k]
    __shared__ f16 Ts[64][72];   // transpose staging [o][n]

    const int t  = threadIdx.x;
    const int n0 = blockIdx.x * 64;
    const int o0 = blockIdx.y * 64;
    const int p  = blockIdx.z % 3;   // 0=q 1=k 2=v
    const int bb = blockIdx.z / 3;

    const float* W    = (p == 0) ? Wq : (p == 1) ? Wk : Wv;
    const float* bias = (p == 0) ? bq : (p == 1) ? bk : bv;

    const int w  = t >> 6;
    const int l  = t & 63;
    const int lr = l & 15;
    const int lg = l >> 4;
    const int wo = (w >> 1) * 32;
    const int wn = (w & 1) * 32;

    const int sl = t & 63;          // staging row (o or n local)
    const int k8 = (t >> 6) * 8;    // staging k offset

    f32x4 acc[2][2] = {};

    for (int ck = 0; ck < CD; ck += 32) {
        __syncthreads();
        {   // A: W[o0+sl][ck+k8 .. +7]  (f32 -> f16)
            const float* s = W + (size_t)(o0 + sl) * CD + ck + k8;
            f16x8 v;
#pragma unroll
            for (int u = 0; u < 8; ++u) v[u] = (f16)s[u];
            *(f16x8*)&As[sl][k8] = v;
        }
        {   // B: x[bb][ck+k8+u][n0+sl]
            const float* s = x + ((size_t)bb * CD + ck + k8) * ND + n0 + sl;
            f16x8 v;
#pragma unroll
            for (int u = 0; u < 8; ++u) v[u] = (f16)s[(size_t)u * ND];
            *(f16x8*)&Bs[sl][k8] = v;
        }
        __syncthreads();
        f16x8 a0 = *(const f16x8*)&As[wo + lr][lg * 8];
        f16x8 a1 = *(const f16x8*)&As[wo + 16 + lr][lg * 8];
        f16x8 b0 = *(const f16x8*)&Bs[wn + lr][lg * 8];
        f16x8 b1 = *(const f16x8*)&Bs[wn + 16 + lr][lg * 8];
        acc[0][0] = __builtin_amdgcn_mfma_f32_16x16x32_f16(a0, b0, acc[0][0], 0, 0, 0);
        acc[0][1] = __builtin_amdgcn_mfma_f32_16x16x32_f16(a0, b1, acc[0][1], 0, 0, 0);
        acc[1][0] = __builtin_amdgcn_mfma_f32_16x16x32_f16(a1, b0, acc[1][0], 0, 0, 0);
        acc[1][1] = __builtin_amdgcn_mfma_f32_16x16x32_f16(a1, b1, acc[1][1], 0, 0, 0);
    }

    if (p < 2) {
        __syncthreads();
#pragma unroll
        for (int so = 0; so < 2; ++so)
#pragma unroll
            for (int r = 0; r < 4; ++r) {
                int orow  = wo + so * 16 + lg * 4 + r;
                float bv_ = bias[o0 + orow];
#pragma unroll
                for (int sn = 0; sn < 2; ++sn)
                    Ts[orow][wn + sn * 16 + lr] = (f16)(acc[so][sn][r] + bv_);
            }
        __syncthreads();
        f16* dst = (p == 0) ? Qt : Kt;
        int n  = t >> 2;          // 0..63
        int o8 = (t & 3) * 16;
        f16 tmp[16];
#pragma unroll
        for (int u = 0; u < 16; ++u) tmp[u] = Ts[o8 + u][n];
        f16* g = dst + ((size_t)bb * ND + n0 + n) * CD + o0 + o8;
        *(f16x8*)g       = *(f16x8*)&tmp[0];
        *(f16x8*)(g + 8) = *(f16x8*)&tmp[8];
    } else {
#pragma unroll
        for (int so = 0; so < 2; ++so)
#pragma unroll
            for (int r = 0; r < 4; ++r) {
                int orow  = wo + so * 16 + lg * 4 + r;
                float bv_ = bias[o0 + orow];
#pragma unroll
                for (int sn = 0; sn < 2; ++sn) {
                    int ncol = wn + sn * 16 + lr;
                    Vb[((size_t)bb * CD + o0 + orow) * ND + n0 + ncol] =
                        (f16)(acc[so][sn][r] + bv_);
                }
            }
    }
}

// ============================================================================
// Kernel 2: flash attention (no scale).  Per block: 4 waves x 16 queries.
// ============================================================================
__global__ __launch_bounds__(256)
void k_attn(const f16* __restrict__ Qt, const f16* __restrict__ Kt,
            const f16* __restrict__ Vb, f16* __restrict__ Hb)
{
    __shared__ f16 Ks[32][264];     // key tile [m][c]
    __shared__ f16 Vs[256][40];     // value tile [c][m]
    __shared__ f16 Ps[4][16][40];   // per-wave P transpose buffer [n][m]

    const int t  = threadIdx.x;
    const int w  = t >> 6;
    const int l  = t & 63;
    const int lr = l & 15;
    const int lg = l >> 4;
    const int bb = blockIdx.y;
    const int q0 = blockIdx.x * 64 + w * 16;

    f16x8 qf[8];
#pragma unroll
    for (int kc = 0; kc < 8; ++kc)
        qf[kc] = *(const f16x8*)(Qt + ((size_t)bb * ND + q0 + lr) * CD + kc * 32 + lg * 8);

    f32x4 oacc[16] = {};
    float row_m[4], row_l[4];
#pragma unroll
    for (int r = 0; r < 4; ++r) { row_m[r] = -3.0e38f; row_l[r] = 0.f; }

    for (int m0 = 0; m0 < ND; m0 += 32) {
        __syncthreads();
        {   // stage K tile [32][256]
            int m  = t >> 3;
            int c0 = (t & 7) * 32;
            const f16* s = Kt + ((size_t)bb * ND + m0 + m) * CD + c0;
#pragma unroll
            for (int u = 0; u < 4; ++u)
                *(f16x8*)&Ks[m][c0 + u * 8] = *(const f16x8*)(s + u * 8);
        }
        {   // stage V tile [256][32]
            const f16* s = Vb + ((size_t)bb * CD + t) * ND + m0;
#pragma unroll
            for (int u = 0; u < 4; ++u)
                *(f16x8*)&Vs[t][u * 8] = *(const f16x8*)(s + u * 8);
        }
        __syncthreads();

        f32x4 s0 = {}, s1 = {};
#pragma unroll
        for (int kc = 0; kc < 8; ++kc) {
            f16x8 k0 = *(const f16x8*)&Ks[lr][kc * 32 + lg * 8];
            f16x8 k1 = *(const f16x8*)&Ks[16 + lr][kc * 32 + lg * 8];
            s0 = __builtin_amdgcn_mfma_f32_16x16x32_f16(qf[kc], k0, s0, 0, 0, 0);
            s1 = __builtin_amdgcn_mfma_f32_16x16x32_f16(qf[kc], k1, s1, 0, 0, 0);
        }

        float scl[4];
#pragma unroll
        for (int r = 0; r < 4; ++r) {
            float v0 = s0[r], v1 = s1[r];
            float pm = fmaxf(v0, v1);
            pm = fmaxf(pm, __shfl_xor(pm, 1));
            pm = fmaxf(pm, __shfl_xor(pm, 2));
            pm = fmaxf(pm, __shfl_xor(pm, 4));
            pm = fmaxf(pm, __shfl_xor(pm, 8));
            float newm = fmaxf(row_m[r], pm);
            float sc   = __expf(row_m[r] - newm);
            float p0   = __expf(v0 - newm);
            float p1   = __expf(v1 - newm);
            float ps   = p0 + p1;
            ps += __shfl_xor(ps, 1);
            ps += __shfl_xor(ps, 2);
            ps += __shfl_xor(ps, 4);
            ps += __shfl_xor(ps, 8);
            row_l[r] = row_l[r] * sc + ps;
            row_m[r] = newm;
            scl[r]   = sc;
            int n = lg * 4 + r;
            Ps[w][n][lr]      = (f16)p0;
            Ps[w][n][16 + lr] = (f16)p1;
        }
        {   // broadcast rescale factor of row lr to this lane
            int src  = (lr >> 2) * 16;
            float t0 = __shfl(scl[0], src);
            float t1 = __shfl(scl[1], src);
            float t2 = __shfl(scl[2], src);
            float t3 = __shfl(scl[3], src);
            int rr   = lr & 3;
            float fa = (rr & 1) ? t1 : t0;
            float fb = (rr & 1) ? t3 : t2;
            float f  = (rr & 2) ? fb : fa;
#pragma unroll
            for (int ct = 0; ct < 16; ++ct) {
                oacc[ct][0] *= f; oacc[ct][1] *= f;
                oacc[ct][2] *= f; oacc[ct][3] *= f;
            }
        }
        f16x8 pfrag = *(const f16x8*)&Ps[w][lr][lg * 8];
#pragma unroll
        for (int ct = 0; ct < 16; ++ct) {
            f16x8 vfrag = *(const f16x8*)&Vs[ct * 16 + lr][lg * 8];
            oacc[ct] = __builtin_amdgcn_mfma_f32_16x16x32_f16(vfrag, pfrag, oacc[ct], 0, 0, 0);
        }
    }

    {
        int src  = (lr >> 2) * 16;
        float t0 = __shfl(row_l[0], src);
        float t1 = __shfl(row_l[1], src);
        float t2 = __shfl(row_l[2], src);
        float t3 = __shfl(row_l[3], src);
        int rr   = lr & 3;
        float fa = (rr & 1) ? t1 : t0;
        float fb = (rr & 1) ? t3 : t2;
        float ls = (rr & 2) ? fb : fa;
        float li = 1.0f / ls;
#pragma unroll
        for (int ct = 0; ct < 16; ++ct) {
            oacc[ct][0] *= li; oacc[ct][1] *= li;
            oacc[ct][2] *= li; oacc[ct][3] *= li;
        }
    }
#pragma unroll
    for (int ct = 0; ct < 16; ++ct)
#pragma unroll
        for (int r = 0; r < 4; ++r) {
            int cch = ct * 16 + lg * 4 + r;
            Hb[((size_t)bb * CD + cch) * ND + q0 + lr] = (f16)oacc[ct][r];
        }
}

// ============================================================================
// Kernel 3: output projection + residual.  Y = Wo@H + bo + x  (f32 out)
// ============================================================================
__global__ __launch_bounds__(256)
void k_proj_o(const f16* __restrict__ Hb, const float* __restrict__ Wo,
              const float* __restrict__ bo, const float* __restrict__ x,
              float* __restrict__ Y)
{
    __shared__ f16 As[64][40];
    __shared__ f16 Bs[64][40];

    const int t  = threadIdx.x;
    const int n0 = blockIdx.x * 64;
    const int o0 = blockIdx.y * 64;
    const int bb = blockIdx.z;

    const int w  = t >> 6;
    const int l  = t & 63;
    const int lr = l & 15;
    const int lg = l >> 4;
    const int wo = (w >> 1) * 32;
    const int wn = (w & 1) * 32;

    const int sl = t & 63;
    const int k8 = (t >> 6) * 8;

    f32x4 acc[2][2] = {};

    for (int ck = 0; ck < CD; ck += 32) {
        __syncthreads();
        {
            const float* s = Wo + (size_t)(o0 + sl) * CD + ck + k8;
            f16x8 v;
#pragma unroll
            for (int u = 0; u < 8; ++u) v[u] = (f16)s[u];
            *(f16x8*)&As[sl][k8] = v;
        }
        {
            const f16* s = Hb + ((size_t)bb * CD + ck + k8) * ND + n0 + sl;
            f16x8 v;
#pragma unroll
            for (int u = 0; u < 8; ++u) v[u] = s[(size_t)u * ND];
            *(f16x8*)&Bs[sl][k8] = v;
        }
        __syncthreads();
        f16x8 a0 = *(const f16x8*)&As[wo + lr][lg * 8];
        f16x8 a1 = *(const f16x8*)&As[wo + 16 + lr][lg * 8];
        f16x8 b0 = *(const f16x8*)&Bs[wn + lr][lg * 8];
        f16x8 b1 = *(const f16x8*)&Bs[wn + 16 + lr][lg * 8];
        acc[0][0] = __builtin_amdgcn_mfma_f32_16x16x32_f16(a0, b0, acc[0][0], 0, 0, 0);
        acc[0][1] = __builtin_amdgcn_mfma_f32_16x16x32_f16(a0, b1, acc[0][1], 0, 0, 0);
        acc[1][0] = __builtin_amdgcn_mfma_f32_16x16x32_f16(a1, b0, acc[1][0], 0, 0, 0);
        acc[1][1] = __builtin_amdgcn_mfma_f32_16x16x32_f16(a1, b1, acc[1][1], 0, 0, 0);
    }

#pragma unroll
    for (int so = 0; so < 2; ++so)
#pragma unroll
        for (int r = 0; r < 4; ++r) {
            int orow  = wo + so * 16 + lg * 4 + r;
            float bv_ = bo[o0 + orow];
#pragma unroll
            for (int sn = 0; sn < 2; ++sn) {
                int ncol   = wn + sn * 16 + lr;
                size_t idx = ((size_t)bb * CD + o0 + orow) * ND + n0 + ncol;
                Y[idx] = acc[so][sn][r] + bv_ + x[idx];
            }
        }
}

// ============================================================================
// Kernel 4: per-(batch,group) mean/rstd over 8 channels x 4096 spatial
// ============================================================================
__global__ __launch_bounds__(256)
void k_stats(const float* __restrict__ Y, float* __restrict__ stats)
{
    const int g = blockIdx.x, b = blockIdx.y;
    const float* base = Y + ((size_t)b * CD + g * 8) * ND;
    float s = 0.f, s2 = 0.f;
    for (int i = threadIdx.x; i < (8 * ND) / 4; i += 256) {
        float4 v = ((const float4*)base)[i];
        s  += v.x + v.y + v.z + v.w;
        s2 += v.x * v.x + v.y * v.y + v.z * v.z + v.w * v.w;
    }
#pragma unroll
    for (int m = 1; m < 64; m <<= 1) {
        s  += __shfl_xor(s, m);
        s2 += __shfl_xor(s2, m);
    }
    __shared__ float red[8];
    if ((threadIdx.x & 63) == 0) {
        red[(threadIdx.x >> 6) * 2]     = s;
        red[(threadIdx.x >> 6) * 2 + 1] = s2;
    }
    __syncthreads();
    if (threadIdx.x == 0) {
        float S  = red[0] + red[2] + red[4] + red[6];
        float S2 = red[1] + red[3] + red[5] + red[7];
        float mean = S / 32768.f;
        float var  = S2 / 32768.f - mean * mean;
        stats[(b * GD + g) * 2]     = mean;
        stats[(b * GD + g) * 2 + 1] = rsqrtf(var + 1e-5f);
    }
}

// ============================================================================
// Kernel 5: normalize + affine + SiLU, write FLOAT32 output
// ============================================================================
__global__ __launch_bounds__(256)
void k_norm_silu(const float* __restrict__ Y, const float* __restrict__ stats,
                 const float* __restrict__ gamma, const float* __restrict__ beta,
                 float* __restrict__ out)
{
    size_t i4 = (size_t)blockIdx.x * 256 + threadIdx.x;   // one float4 each
    int c = (int)((i4 / (ND / 4)) % CD);
    int b = (int)(i4 / ((size_t)CD * (ND / 4)));
    float mean = stats[(b * GD + c / 8) * 2];
    float rstd = stats[(b * GD + c / 8) * 2 + 1];
    float ga = gamma[c], be = beta[c];
    float4 v = ((const float4*)Y)[i4];
    float in[4] = { v.x, v.y, v.z, v.w };
    float ob[4];
#pragma unroll
    for (int u = 0; u < 4; ++u) {
        float yn = (in[u] - mean) * rstd * ga + be;
        float sg = 1.0f / (1.0f + __expf(-yn));
        ob[u] = yn * sg;
    }
    *(float4*)(out + i4 * 4) = *(float4*)ob;
}

// ============================================================================
extern "C" void kernel_launch(void* const* d_in, const int* in_sizes, int n_in,
                              void* d_out, int out_size, void* d_ws, size_t ws_size,
                              hipStream_t stream)
{
    const float* x     = (const float*)d_in[0];
    const float* Wq    = (const float*)d_in[1];
    const float* bq    = (const float*)d_in[2];
    const float* Wk    = (const float*)d_in[3];
    const float* bk    = (const float*)d_in[4];
    const float* Wv    = (const float*)d_in[5];
    const float* bv    = (const float*)d_in[6];
    const float* Wo    = (const float*)d_in[7];
    const float* bo    = (const float*)d_in[8];
    const float* gamma = (const float*)d_in[9];
    const float* beta  = (const float*)d_in[10];

    char* ws = (char*)d_ws;
    f16*   Qt    = (f16*)(ws);                      //  4 MiB  [B][N][C]
    f16*   Kt    = (f16*)(ws + (4u << 20));         //  4 MiB  [B][N][C]
    f16*   Vb    = (f16*)(ws + (8u << 20));         //  4 MiB  [B][C][N]
    f16*   Hb    = (f16*)(ws + (12u << 20));        //  4 MiB  [B][C][N]
    float* Y     = (float*)(ws + (16u << 20));      //  8 MiB  [B][C][N]
    float* stats = (float*)(ws + (24u << 20));      //  512 B

    k_proj_qkv<<<dim3(64, 4, 6), 256, 0, stream>>>(x, Wq, bq, Wk, bk, Wv, bv, Qt, Kt, Vb);
    k_attn<<<dim3(64, 2), 256, 0, stream>>>(Qt, Kt, Vb, Hb);
    k_proj_o<<<dim3(64, 4, 2), 256, 0, stream>>>(Hb, Wo, bo, x, Y);
    k_stats<<<dim3(32, 2), 256, 0, stream>>>(Y, stats);
    k_norm_silu<<<2048, 256, 0, stream>>>(Y, stats, gamma, beta, (float*)d_out);
}

// Round 3
// 128.220 us; speedup vs baseline: 2.7210x; 2.7210x over previous
//
#include <hip/hip_runtime.h>
#include <hip/hip_bf16.h>

typedef _Float16 f16;
typedef __attribute__((ext_vector_type(8))) _Float16 f16x8;
typedef __attribute__((ext_vector_type(4))) float f32x4;

#define CD 256
#define ND 4096
#define GD 32
#define KS 4            // key splits for flash-decode
#define KVB 64          // keys per iteration

// async global->LDS, 16B per lane, lds dest must be wave-uniform base
__device__ __forceinline__ void gl_lds16(const f16* g, f16* l) {
    __builtin_amdgcn_global_load_lds(
        (const __attribute__((address_space(1))) unsigned int*)g,
        (__attribute__((address_space(3))) unsigned int*)l,
        16, 0, 0);
}

// ============================================================================
// Kernel 1: QKV projection.  q[b,o,n] = sum_c W[o,c] x[b,c,n] + bias[o]
// Q,K written TRANSPOSED [b][n][c] f16; V natural [b][c][n] f16.
// ============================================================================
__global__ __launch_bounds__(256)
void k_proj_qkv(const float* __restrict__ x,
                const float* __restrict__ Wq, const float* __restrict__ bq,
                const float* __restrict__ Wk, const float* __restrict__ bk,
                const float* __restrict__ Wv, const float* __restrict__ bv,
                f16* __restrict__ Qt, f16* __restrict__ Kt, f16* __restrict__ Vb)
{
    __shared__ f16 As[64][40];
    __shared__ f16 Bs[64][40];
    __shared__ f16 Ts[64][72];

    const int t  = threadIdx.x;
    const int n0 = blockIdx.x * 64;
    const int o0 = blockIdx.y * 64;
    const int p  = blockIdx.z % 3;
    const int bb = blockIdx.z / 3;

    const float* W    = (p == 0) ? Wq : (p == 1) ? Wk : Wv;
    const float* bias = (p == 0) ? bq : (p == 1) ? bk : bv;

    const int w  = t >> 6;
    const int l  = t & 63;
    const int lr = l & 15;
    const int lg = l >> 4;
    const int wo = (w >> 1) * 32;
    const int wn = (w & 1) * 32;

    const int sl = t & 63;
    const int k8 = (t >> 6) * 8;

    f32x4 acc[2][2] = {};

    for (int ck = 0; ck < CD; ck += 32) {
        __syncthreads();
        {
            const float* s = W + (size_t)(o0 + sl) * CD + ck + k8;
            f16x8 v;
#pragma unroll
            for (int u = 0; u < 8; ++u) v[u] = (f16)s[u];
            *(f16x8*)&As[sl][k8] = v;
        }
        {
            const float* s = x + ((size_t)bb * CD + ck + k8) * ND + n0 + sl;
            f16x8 v;
#pragma unroll
            for (int u = 0; u < 8; ++u) v[u] = (f16)s[(size_t)u * ND];
            *(f16x8*)&Bs[sl][k8] = v;
        }
        __syncthreads();
        f16x8 a0 = *(const f16x8*)&As[wo + lr][lg * 8];
        f16x8 a1 = *(const f16x8*)&As[wo + 16 + lr][lg * 8];
        f16x8 b0 = *(const f16x8*)&Bs[wn + lr][lg * 8];
        f16x8 b1 = *(const f16x8*)&Bs[wn + 16 + lr][lg * 8];
        acc[0][0] = __builtin_amdgcn_mfma_f32_16x16x32_f16(a0, b0, acc[0][0], 0, 0, 0);
        acc[0][1] = __builtin_amdgcn_mfma_f32_16x16x32_f16(a0, b1, acc[0][1], 0, 0, 0);
        acc[1][0] = __builtin_amdgcn_mfma_f32_16x16x32_f16(a1, b0, acc[1][0], 0, 0, 0);
        acc[1][1] = __builtin_amdgcn_mfma_f32_16x16x32_f16(a1, b1, acc[1][1], 0, 0, 0);
    }

    if (p < 2) {
        __syncthreads();
#pragma unroll
        for (int so = 0; so < 2; ++so)
#pragma unroll
            for (int r = 0; r < 4; ++r) {
                int orow  = wo + so * 16 + lg * 4 + r;
                float bv_ = bias[o0 + orow];
#pragma unroll
                for (int sn = 0; sn < 2; ++sn)
                    Ts[orow][wn + sn * 16 + lr] = (f16)(acc[so][sn][r] + bv_);
            }
        __syncthreads();
        f16* dst = (p == 0) ? Qt : Kt;
        int n  = t >> 2;
        int o8 = (t & 3) * 16;
        f16 tmp[16];
#pragma unroll
        for (int u = 0; u < 16; ++u) tmp[u] = Ts[o8 + u][n];
        f16* g = dst + ((size_t)bb * ND + n0 + n) * CD + o0 + o8;
        *(f16x8*)g       = *(f16x8*)&tmp[0];
        *(f16x8*)(g + 8) = *(f16x8*)&tmp[8];
    } else {
#pragma unroll
        for (int so = 0; so < 2; ++so)
#pragma unroll
            for (int r = 0; r < 4; ++r) {
                int orow  = wo + so * 16 + lg * 4 + r;
                float bv_ = bias[o0 + orow];
#pragma unroll
                for (int sn = 0; sn < 2; ++sn) {
                    int ncol = wn + sn * 16 + lr;
                    Vb[((size_t)bb * CD + o0 + orow) * ND + n0 + ncol] =
                        (f16)(acc[so][sn][r] + bv_);
                }
            }
    }
}

// ============================================================================
// Kernel 2: flash attention with split-K.
// Block: 4 waves x 16 queries (QBLK=64); each block covers ND/KS keys in
// KVB=64-key iterations.  K/V staged via global_load_lds into XOR-swizzled
// LDS (linear dest, pre-swizzled global source; swizzled ds_read).
// Writes unnormalized O partial (f16) + per-row (m,l) (f32).
// ============================================================================
__global__ __launch_bounds__(256, 2)
void k_attn(const f16* __restrict__ Qt, const f16* __restrict__ Kt,
            const f16* __restrict__ Vb, f16* __restrict__ Op,
            float* __restrict__ ml)
{
    __shared__ f16 Ks[64 * 256];    // [row][chunk^(row&7)] 16B chunks, 32 KB
    __shared__ f16 Vs[256 * 64];    // [c][chunk^(c&7)], 32 KB
    __shared__ f16 Ps[4][16][72];   // per-wave P transpose buffer

    const int t  = threadIdx.x;
    const int w  = t >> 6;
    const int l  = t & 63;
    const int lr = l & 15;
    const int lg = l >> 4;
    const int ks = blockIdx.y;
    const int bb = blockIdx.z;
    const int q0 = blockIdx.x * 64 + w * 16;

    // Q fragments in registers
    f16x8 qf[8];
#pragma unroll
    for (int kc = 0; kc < 8; ++kc)
        qf[kc] = *(const f16x8*)(Qt + ((size_t)bb * ND + q0 + lr) * CD + kc * 32 + lg * 8);

    f32x4 oacc[16] = {};
    float row_m[4], row_l[4];
#pragma unroll
    for (int r = 0; r < 4; ++r) { row_m[r] = -3.0e38f; row_l[r] = 0.f; }

    const int kv0 = ks * (ND / KS);

    for (int it = 0; it < (ND / KS) / KVB; ++it) {
        const int m0 = kv0 + it * KVB;
        __syncthreads();   // previous compute done reading LDS
        {   // stage K tile [64][256] — contiguous 32KB of Kt, swizzled source
            const f16* kt = Kt + ((size_t)bb * ND + m0) * CD;
#pragma unroll
            for (int j = 0; j < 8; ++j) {
                int v   = (w * 8 + j) * 64 + l;
                int row = v >> 5;
                int ch  = (v & 31) ^ (row & 7);
                gl_lds16(kt + (size_t)row * CD + ch * 8, Ks + (w * 8 + j) * 512);
            }
        }
        {   // stage V tile [256][64]
            const f16* vb = Vb + (size_t)bb * CD * ND + m0;
#pragma unroll
            for (int j = 0; j < 8; ++j) {
                int v = (w * 8 + j) * 64 + l;
                int c = v >> 3;
                int u = (v & 7) ^ (c & 7);
                gl_lds16(vb + (size_t)c * ND + u * 8, Vs + (w * 8 + j) * 512);
            }
        }
        __syncthreads();   // compiler drains vmcnt before s_barrier

        // ---- scores: 4 m-subtiles of 16 ----
        f32x4 s[4] = {};
#pragma unroll
        for (int kc = 0; kc < 8; ++kc) {
#pragma unroll
            for (int sub = 0; sub < 4; ++sub) {
                int row = sub * 16 + lr;
                f16x8 kf = *(const f16x8*)&Ks[row * 256 + (((kc * 4 + lg) ^ (lr & 7))) * 8];
                s[sub] = __builtin_amdgcn_mfma_f32_16x16x32_f16(qf[kc], kf, s[sub], 0, 0, 0);
            }
        }

        // ---- online softmax ----
        float scl[4];
#pragma unroll
        for (int r = 0; r < 4; ++r) {
            float v0 = s[0][r], v1 = s[1][r], v2 = s[2][r], v3 = s[3][r];
            float pm = fmaxf(fmaxf(v0, v1), fmaxf(v2, v3));
            pm = fmaxf(pm, __shfl_xor(pm, 1));
            pm = fmaxf(pm, __shfl_xor(pm, 2));
            pm = fmaxf(pm, __shfl_xor(pm, 4));
            pm = fmaxf(pm, __shfl_xor(pm, 8));
            float newm = fmaxf(row_m[r], pm);
            float sc   = __expf(row_m[r] - newm);
            float p0   = __expf(v0 - newm);
            float p1   = __expf(v1 - newm);
            float p2   = __expf(v2 - newm);
            float p3   = __expf(v3 - newm);
            float ps   = p0 + p1 + p2 + p3;
            ps += __shfl_xor(ps, 1);
            ps += __shfl_xor(ps, 2);
            ps += __shfl_xor(ps, 4);
            ps += __shfl_xor(ps, 8);
            row_l[r] = row_l[r] * sc + ps;
            row_m[r] = newm;
            scl[r]   = sc;
            int n = lg * 4 + r;
            Ps[w][n][lr]      = (f16)p0;
            Ps[w][n][16 + lr] = (f16)p1;
            Ps[w][n][32 + lr] = (f16)p2;
            Ps[w][n][48 + lr] = (f16)p3;
        }
        {   // broadcast rescale factor of row lr to this lane (O cols are n=lr)
            int src  = (lr >> 2) * 16;
            float t0 = __shfl(scl[0], src);
            float t1 = __shfl(scl[1], src);
            float t2 = __shfl(scl[2], src);
            float t3 = __shfl(scl[3], src);
            int rr   = lr & 3;
            float fa = (rr & 1) ? t1 : t0;
            float fb = (rr & 1) ? t3 : t2;
            float f  = (rr & 2) ? fb : fa;
#pragma unroll
            for (int ct = 0; ct < 16; ++ct) {
                oacc[ct][0] *= f; oacc[ct][1] *= f;
                oacc[ct][2] *= f; oacc[ct][3] *= f;
            }
        }
        // ---- PV: O[c][n] += V[c][m] * P[n][m], 2 m-chunks of 32 ----
#pragma unroll
        for (int mc = 0; mc < 2; ++mc) {
            f16x8 pf = *(const f16x8*)&Ps[w][lr][mc * 32 + lg * 8];
#pragma unroll
            for (int ct = 0; ct < 16; ++ct) {
                f16x8 vf = *(const f16x8*)&Vs[(ct * 16 + lr) * 64 + (((mc * 4 + lg) ^ (lr & 7))) * 8];
                oacc[ct] = __builtin_amdgcn_mfma_f32_16x16x32_f16(vf, pf, oacc[ct], 0, 0, 0);
            }
        }
    }

    // ---- write unnormalized partial + (m,l) ----
#pragma unroll
    for (int ct = 0; ct < 16; ++ct)
#pragma unroll
        for (int r = 0; r < 4; ++r) {
            int cch = ct * 16 + lg * 4 + r;
            Op[(((size_t)ks * 2 + bb) * CD + cch) * ND + q0 + lr] = (f16)oacc[ct][r];
        }
    if (lr == 0) {
#pragma unroll
        for (int r = 0; r < 4; ++r) {
            int n = q0 + lg * 4 + r;
            ml[((ks * 2 + bb) * 2 + 0) * ND + n] = row_m[r];
            ml[((ks * 2 + bb) * 2 + 1) * ND + n] = row_l[r];
        }
    }
}

// ============================================================================
// Kernel 2b: combine split-K partials -> Hb[b][c][n] f16
// ============================================================================
__global__ __launch_bounds__(256)
void k_comb(const f16* __restrict__ Op, const float* __restrict__ ml,
            f16* __restrict__ Hb)
{
    const int t  = threadIdx.x;
    const int tn = t & 63;
    const int cg = t >> 6;
    const int n  = blockIdx.x * 64 + tn;
    const int b  = blockIdx.y;

    float m[KS], lv[KS];
#pragma unroll
    for (int ks = 0; ks < KS; ++ks) {
        m[ks]  = ml[((ks * 2 + b) * 2 + 0) * ND + n];
        lv[ks] = ml[((ks * 2 + b) * 2 + 1) * ND + n];
    }
    float M = fmaxf(fmaxf(m[0], m[1]), fmaxf(m[2], m[3]));
    float wgt[KS];
    float L = 0.f;
#pragma unroll
    for (int ks = 0; ks < KS; ++ks) { wgt[ks] = __expf(m[ks] - M); L += wgt[ks] * lv[ks]; }
    float inv = 1.0f / L;

#pragma unroll 4
    for (int i = 0; i < 64; ++i) {
        int c = cg * 64 + i;
        float acc = 0.f;
#pragma unroll
        for (int ks = 0; ks < KS; ++ks)
            acc += wgt[ks] * (float)Op[(((size_t)ks * 2 + b) * CD + c) * ND + n];
        Hb[((size_t)b * CD + c) * ND + n] = (f16)(acc * inv);
    }
}

// ============================================================================
// Kernel 3: output projection + residual.  Y = Wo@H + bo + x  (f32 out)
// ============================================================================
__global__ __launch_bounds__(256)
void k_proj_o(const f16* __restrict__ Hb, const float* __restrict__ Wo,
              const float* __restrict__ bo, const float* __restrict__ x,
              float* __restrict__ Y)
{
    __shared__ f16 As[64][40];
    __shared__ f16 Bs[64][40];

    const int t  = threadIdx.x;
    const int n0 = blockIdx.x * 64;
    const int o0 = blockIdx.y * 64;
    const int bb = blockIdx.z;

    const int w  = t >> 6;
    const int l  = t & 63;
    const int lr = l & 15;
    const int lg = l >> 4;
    const int wo = (w >> 1) * 32;
    const int wn = (w & 1) * 32;

    const int sl = t & 63;
    const int k8 = (t >> 6) * 8;

    f32x4 acc[2][2] = {};

    for (int ck = 0; ck < CD; ck += 32) {
        __syncthreads();
        {
            const float* s = Wo + (size_t)(o0 + sl) * CD + ck + k8;
            f16x8 v;
#pragma unroll
            for (int u = 0; u < 8; ++u) v[u] = (f16)s[u];
            *(f16x8*)&As[sl][k8] = v;
        }
        {
            const f16* s = Hb + ((size_t)bb * CD + ck + k8) * ND + n0 + sl;
            f16x8 v;
#pragma unroll
            for (int u = 0; u < 8; ++u) v[u] = s[(size_t)u * ND];
            *(f16x8*)&Bs[sl][k8] = v;
        }
        __syncthreads();
        f16x8 a0 = *(const f16x8*)&As[wo + lr][lg * 8];
        f16x8 a1 = *(const f16x8*)&As[wo + 16 + lr][lg * 8];
        f16x8 b0 = *(const f16x8*)&Bs[wn + lr][lg * 8];
        f16x8 b1 = *(const f16x8*)&Bs[wn + 16 + lr][lg * 8];
        acc[0][0] = __builtin_amdgcn_mfma_f32_16x16x32_f16(a0, b0, acc[0][0], 0, 0, 0);
        acc[0][1] = __builtin_amdgcn_mfma_f32_16x16x32_f16(a0, b1, acc[0][1], 0, 0, 0);
        acc[1][0] = __builtin_amdgcn_mfma_f32_16x16x32_f16(a1, b0, acc[1][0], 0, 0, 0);
        acc[1][1] = __builtin_amdgcn_mfma_f32_16x16x32_f16(a1, b1, acc[1][1], 0, 0, 0);
    }

#pragma unroll
    for (int so = 0; so < 2; ++so)
#pragma unroll
        for (int r = 0; r < 4; ++r) {
            int orow  = wo + so * 16 + lg * 4 + r;
            float bv_ = bo[o0 + orow];
#pragma unroll
            for (int sn = 0; sn < 2; ++sn) {
                int ncol   = wn + sn * 16 + lr;
                size_t idx = ((size_t)bb * CD + o0 + orow) * ND + n0 + ncol;
                Y[idx] = acc[so][sn][r] + bv_ + x[idx];
            }
        }
}

// ============================================================================
// Kernel 4: per-(batch,group) mean/rstd
// ============================================================================
__global__ __launch_bounds__(256)
void k_stats(const float* __restrict__ Y, float* __restrict__ stats)
{
    const int g = blockIdx.x, b = blockIdx.y;
    const float* base = Y + ((size_t)b * CD + g * 8) * ND;
    float s = 0.f, s2 = 0.f;
    for (int i = threadIdx.x; i < (8 * ND) / 4; i += 256) {
        float4 v = ((const float4*)base)[i];
        s  += v.x + v.y + v.z + v.w;
        s2 += v.x * v.x + v.y * v.y + v.z * v.z + v.w * v.w;
    }
#pragma unroll
    for (int m = 1; m < 64; m <<= 1) {
        s  += __shfl_xor(s, m);
        s2 += __shfl_xor(s2, m);
    }
    __shared__ float red[8];
    if ((threadIdx.x & 63) == 0) {
        red[(threadIdx.x >> 6) * 2]     = s;
        red[(threadIdx.x >> 6) * 2 + 1] = s2;
    }
    __syncthreads();
    if (threadIdx.x == 0) {
        float S  = red[0] + red[2] + red[4] + red[6];
        float S2 = red[1] + red[3] + red[5] + red[7];
        float mean = S / 32768.f;
        float var  = S2 / 32768.f - mean * mean;
        stats[(b * GD + g) * 2]     = mean;
        stats[(b * GD + g) * 2 + 1] = rsqrtf(var + 1e-5f);
    }
}

// ============================================================================
// Kernel 5: normalize + affine + SiLU, f32 out
// ============================================================================
__global__ __launch_bounds__(256)
void k_norm_silu(const float* __restrict__ Y, const float* __restrict__ stats,
                 const float* __restrict__ gamma, const float* __restrict__ beta,
                 float* __restrict__ out)
{
    size_t i4 = (size_t)blockIdx.x * 256 + threadIdx.x;
    int c = (int)((i4 / (ND / 4)) % CD);
    int b = (int)(i4 / ((size_t)CD * (ND / 4)));
    float mean = stats[(b * GD + c / 8) * 2];
    float rstd = stats[(b * GD + c / 8) * 2 + 1];
    float ga = gamma[c], be = beta[c];
    float4 v = ((const float4*)Y)[i4];
    float in[4] = { v.x, v.y, v.z, v.w };
    float ob[4];
#pragma unroll
    for (int u = 0; u < 4; ++u) {
        float yn = (in[u] - mean) * rstd * ga + be;
        float sg = 1.0f / (1.0f + __expf(-yn));
        ob[u] = yn * sg;
    }
    *(float4*)(out + i4 * 4) = *(float4*)ob;
}

// ============================================================================
extern "C" void kernel_launch(void* const* d_in, const int* in_sizes, int n_in,
                              void* d_out, int out_size, void* d_ws, size_t ws_size,
                              hipStream_t stream)
{
    const float* x     = (const float*)d_in[0];
    const float* Wq    = (const float*)d_in[1];
    const float* bq    = (const float*)d_in[2];
    const float* Wk    = (const float*)d_in[3];
    const float* bk    = (const float*)d_in[4];
    const float* Wv    = (const float*)d_in[5];
    const float* bv    = (const float*)d_in[6];
    const float* Wo    = (const float*)d_in[7];
    const float* bo    = (const float*)d_in[8];
    const float* gamma = (const float*)d_in[9];
    const float* beta  = (const float*)d_in[10];

    char* ws = (char*)d_ws;
    f16*   Qt    = (f16*)(ws);                       //  0..4 MiB   [B][N][C]
    f16*   Kt    = (f16*)(ws + (4u << 20));          //  4..8 MiB   [B][N][C]
    f16*   Vb    = (f16*)(ws + (8u << 20));          //  8..12 MiB  [B][C][N]
    f16*   Hb    = (f16*)(ws + (12u << 20));         // 12..16 MiB  [B][C][N]
    f16*   Op    = (f16*)(ws + (16u << 20));         // 16..32 MiB  [KS][B][C][N]
    float* ml    = (float*)(ws + (32u << 20));       // 32..32.5 MiB [KS][B][2][N]
    float* Y     = (float*)(ws + (16u << 20));       // reuses Op region after combine
    float* stats = (float*)(ws + (33u << 20));       // 512 B

    k_proj_qkv<<<dim3(64, 4, 6), 256, 0, stream>>>(x, Wq, bq, Wk, bk, Wv, bv, Qt, Kt, Vb);
    k_attn<<<dim3(64, KS, 2), 256, 0, stream>>>(Qt, Kt, Vb, Op, ml);
    k_comb<<<dim3(64, 2), 256, 0, stream>>>(Op, ml, Hb);
    k_proj_o<<<dim3(64, 4, 2), 256, 0, stream>>>(Hb, Wo, bo, x, Y);
    k_stats<<<dim3(32, 2), 256, 0, stream>>>(Y, stats);
    k_norm_silu<<<2048, 256, 0, stream>>>(Y, stats, gamma, beta, (float*)d_out);
}

// Round 4
// 126.263 us; speedup vs baseline: 2.7632x; 1.0155x over previous
//
#include <hip/hip_runtime.h>
#include <hip/hip_bf16.h>

typedef _Float16 f16;
typedef __attribute__((ext_vector_type(8))) _Float16 f16x8;
typedef __attribute__((ext_vector_type(4))) float f32x4;

#define CD 256
#define ND 4096
#define GD 32
#define KS 4            // key splits for flash-decode
#define KVB 64          // keys per iteration
#define NIT ((ND / KS) / KVB)

// async global->LDS, 16B per lane, lds dest must be wave-uniform base
__device__ __forceinline__ void gl_lds16(const f16* g, f16* l) {
    __builtin_amdgcn_global_load_lds(
        (const __attribute__((address_space(1))) unsigned int*)g,
        (__attribute__((address_space(3))) unsigned int*)l,
        16, 0, 0);
}

// ============================================================================
// Kernel 1: QKV projection.  q[b,o,n] = sum_c W[o,c] x[b,c,n] + bias[o]
// Q,K written TRANSPOSED [b][n][c] f16; V natural [b][c][n] f16.
// ============================================================================
__global__ __launch_bounds__(256)
void k_proj_qkv(const float* __restrict__ x,
                const float* __restrict__ Wq, const float* __restrict__ bq,
                const float* __restrict__ Wk, const float* __restrict__ bk,
                const float* __restrict__ Wv, const float* __restrict__ bv,
                f16* __restrict__ Qt, f16* __restrict__ Kt, f16* __restrict__ Vb)
{
    __shared__ f16 As[64][40];
    __shared__ f16 Bs[64][40];
    __shared__ f16 Ts[64][72];

    const int t  = threadIdx.x;
    const int n0 = blockIdx.x * 64;
    const int o0 = blockIdx.y * 64;
    const int p  = blockIdx.z % 3;
    const int bb = blockIdx.z / 3;

    const float* W    = (p == 0) ? Wq : (p == 1) ? Wk : Wv;
    const float* bias = (p == 0) ? bq : (p == 1) ? bk : bv;

    const int w  = t >> 6;
    const int l  = t & 63;
    const int lr = l & 15;
    const int lg = l >> 4;
    const int wo = (w >> 1) * 32;
    const int wn = (w & 1) * 32;

    const int sl = t & 63;
    const int k8 = (t >> 6) * 8;

    f32x4 acc[2][2] = {};

    for (int ck = 0; ck < CD; ck += 32) {
        __syncthreads();
        {
            const float* s = W + (size_t)(o0 + sl) * CD + ck + k8;
            f16x8 v;
#pragma unroll
            for (int u = 0; u < 8; ++u) v[u] = (f16)s[u];
            *(f16x8*)&As[sl][k8] = v;
        }
        {
            const float* s = x + ((size_t)bb * CD + ck + k8) * ND + n0 + sl;
            f16x8 v;
#pragma unroll
            for (int u = 0; u < 8; ++u) v[u] = (f16)s[(size_t)u * ND];
            *(f16x8*)&Bs[sl][k8] = v;
        }
        __syncthreads();
        f16x8 a0 = *(const f16x8*)&As[wo + lr][lg * 8];
        f16x8 a1 = *(const f16x8*)&As[wo + 16 + lr][lg * 8];
        f16x8 b0 = *(const f16x8*)&Bs[wn + lr][lg * 8];
        f16x8 b1 = *(const f16x8*)&Bs[wn + 16 + lr][lg * 8];
        acc[0][0] = __builtin_amdgcn_mfma_f32_16x16x32_f16(a0, b0, acc[0][0], 0, 0, 0);
        acc[0][1] = __builtin_amdgcn_mfma_f32_16x16x32_f16(a0, b1, acc[0][1], 0, 0, 0);
        acc[1][0] = __builtin_amdgcn_mfma_f32_16x16x32_f16(a1, b0, acc[1][0], 0, 0, 0);
        acc[1][1] = __builtin_amdgcn_mfma_f32_16x16x32_f16(a1, b1, acc[1][1], 0, 0, 0);
    }

    if (p < 2) {
        __syncthreads();
#pragma unroll
        for (int so = 0; so < 2; ++so)
#pragma unroll
            for (int r = 0; r < 4; ++r) {
                int orow  = wo + so * 16 + lg * 4 + r;
                float bv_ = bias[o0 + orow];
#pragma unroll
                for (int sn = 0; sn < 2; ++sn)
                    Ts[orow][wn + sn * 16 + lr] = (f16)(acc[so][sn][r] + bv_);
            }
        __syncthreads();
        f16* dst = (p == 0) ? Qt : Kt;
        int n  = t >> 2;
        int o8 = (t & 3) * 16;
        f16 tmp[16];
#pragma unroll
        for (int u = 0; u < 16; ++u) tmp[u] = Ts[o8 + u][n];
        f16* g = dst + ((size_t)bb * ND + n0 + n) * CD + o0 + o8;
        *(f16x8*)g       = *(f16x8*)&tmp[0];
        *(f16x8*)(g + 8) = *(f16x8*)&tmp[8];
    } else {
#pragma unroll
        for (int so = 0; so < 2; ++so)
#pragma unroll
            for (int r = 0; r < 4; ++r) {
                int orow  = wo + so * 16 + lg * 4 + r;
                float bv_ = bias[o0 + orow];
#pragma unroll
                for (int sn = 0; sn < 2; ++sn) {
                    int ncol = wn + sn * 16 + lr;
                    Vb[((size_t)bb * CD + o0 + orow) * ND + n0 + ncol] =
                        (f16)(acc[so][sn][r] + bv_);
                }
            }
    }
}

// ============================================================================
// Kernel 2: flash attention with split-K.  8 waves x 16 queries (QBLK=128).
// KVB=64 keys/iter, K/V double-buffered in LDS (one barrier per iter);
// staged via global_load_lds, XOR-swizzled (pre-swizzled global source,
// linear LDS dest, swizzled ds_read).  Writes unnormalized O partial (f16)
// + per-row (m,l) (f32).
// ============================================================================
__global__ __launch_bounds__(512, 2)
void k_attn(const f16* __restrict__ Qt, const f16* __restrict__ Kt,
            const f16* __restrict__ Vb, f16* __restrict__ Op,
            float* __restrict__ ml)
{
    __shared__ f16 Ks[2][64 * 256];  // [buf][row][chunk^(row&7)]  2x32 KB
    __shared__ f16 Vs[2][256 * 64];  // [buf][c][chunk^(c&7)]      2x32 KB
    __shared__ f16 Ps[8][16][72];    // per-wave P transpose buffer, 18 KB

    const int t  = threadIdx.x;
    const int w  = t >> 6;          // 0..7
    const int l  = t & 63;
    const int lr = l & 15;
    const int lg = l >> 4;
    const int ks = blockIdx.y;
    const int bb = blockIdx.z;
    const int q0 = blockIdx.x * 128 + w * 16;

    // Q fragments in registers
    f16x8 qf[8];
#pragma unroll
    for (int kc = 0; kc < 8; ++kc)
        qf[kc] = *(const f16x8*)(Qt + ((size_t)bb * ND + q0 + lr) * CD + kc * 32 + lg * 8);

    f32x4 oacc[16] = {};
    float row_m[4], row_l[4];
#pragma unroll
    for (int r = 0; r < 4; ++r) { row_m[r] = -3.0e38f; row_l[r] = 0.f; }

    const int kv0 = ks * (ND / KS);
    const f16* ktb = Kt + (size_t)bb * ND * CD;
    const f16* vbb = Vb + (size_t)bb * CD * ND;

    // ---- stage tile at key-offset m0 into buffer bi (per-wave 8x 1KB loads)
    auto stage = [&](int m0, int bi) {
#pragma unroll
        for (int j = 0; j < 4; ++j) {       // K tile [64][256]
            int v   = (w * 4 + j) * 64 + l;
            int row = v >> 5;
            int ch  = (v & 31) ^ (row & 7);
            gl_lds16(ktb + (size_t)(m0 + row) * CD + ch * 8,
                     &Ks[bi][(w * 4 + j) * 512]);
        }
#pragma unroll
        for (int j = 0; j < 4; ++j) {       // V tile [256][64]
            int v = (w * 4 + j) * 64 + l;
            int c = v >> 3;
            int u = (v & 7) ^ (c & 7);
            gl_lds16(vbb + (size_t)c * ND + m0 + u * 8,
                     &Vs[bi][(w * 4 + j) * 512]);
        }
    };

    stage(kv0, 0);
    __syncthreads();    // drains vmcnt; tile 0 resident

    for (int it = 0; it < NIT; ++it) {
        const int bi = it & 1;
        if (it + 1 < NIT) stage(kv0 + (it + 1) * KVB, bi ^ 1);

        // ---- scores: 4 m-subtiles of 16 ----
        f32x4 s[4] = {};
#pragma unroll
        for (int kc = 0; kc < 8; ++kc) {
#pragma unroll
            for (int sub = 0; sub < 4; ++sub) {
                int row = sub * 16 + lr;
                f16x8 kf = *(const f16x8*)&Ks[bi][row * 256 + (((kc * 4 + lg) ^ (lr & 7))) * 8];
                s[sub] = __builtin_amdgcn_mfma_f32_16x16x32_f16(qf[kc], kf, s[sub], 0, 0, 0);
            }
        }

        // ---- online softmax ----
        float scl[4];
#pragma unroll
        for (int r = 0; r < 4; ++r) {
            float v0 = s[0][r], v1 = s[1][r], v2 = s[2][r], v3 = s[3][r];
            float pm = fmaxf(fmaxf(v0, v1), fmaxf(v2, v3));
            pm = fmaxf(pm, __shfl_xor(pm, 1));
            pm = fmaxf(pm, __shfl_xor(pm, 2));
            pm = fmaxf(pm, __shfl_xor(pm, 4));
            pm = fmaxf(pm, __shfl_xor(pm, 8));
            float newm = fmaxf(row_m[r], pm);
            float sc   = __expf(row_m[r] - newm);
            float p0   = __expf(v0 - newm);
            float p1   = __expf(v1 - newm);
            float p2   = __expf(v2 - newm);
            float p3   = __expf(v3 - newm);
            float ps   = p0 + p1 + p2 + p3;
            ps += __shfl_xor(ps, 1);
            ps += __shfl_xor(ps, 2);
            ps += __shfl_xor(ps, 4);
            ps += __shfl_xor(ps, 8);
            row_l[r] = row_l[r] * sc + ps;
            row_m[r] = newm;
            scl[r]   = sc;
            int n = lg * 4 + r;
            Ps[w][n][lr]      = (f16)p0;
            Ps[w][n][16 + lr] = (f16)p1;
            Ps[w][n][32 + lr] = (f16)p2;
            Ps[w][n][48 + lr] = (f16)p3;
        }
        {   // broadcast rescale factor of row lr to this lane (O cols are n=lr)
            int src  = (lr >> 2) * 16;
            float t0 = __shfl(scl[0], src);
            float t1 = __shfl(scl[1], src);
            float t2 = __shfl(scl[2], src);
            float t3 = __shfl(scl[3], src);
            int rr   = lr & 3;
            float fa = (rr & 1) ? t1 : t0;
            float fb = (rr & 1) ? t3 : t2;
            float f  = (rr & 2) ? fb : fa;
#pragma unroll
            for (int ct = 0; ct < 16; ++ct) {
                oacc[ct][0] *= f; oacc[ct][1] *= f;
                oacc[ct][2] *= f; oacc[ct][3] *= f;
            }
        }
        // ---- PV: O[c][n] += V[c][m] * P[n][m], 2 m-chunks of 32 ----
#pragma unroll
        for (int mc = 0; mc < 2; ++mc) {
            f16x8 pf = *(const f16x8*)&Ps[w][lr][mc * 32 + lg * 8];
#pragma unroll
            for (int ct = 0; ct < 16; ++ct) {
                f16x8 vf = *(const f16x8*)&Vs[bi][(ct * 16 + lr) * 64 + (((mc * 4 + lg) ^ (lr & 7))) * 8];
                oacc[ct] = __builtin_amdgcn_mfma_f32_16x16x32_f16(vf, pf, oacc[ct], 0, 0, 0);
            }
        }
        __syncthreads();   // drains stage(it+1); frees buffers for next iter
    }

    // ---- write unnormalized partial + (m,l) ----
#pragma unroll
    for (int ct = 0; ct < 16; ++ct)
#pragma unroll
        for (int r = 0; r < 4; ++r) {
            int cch = ct * 16 + lg * 4 + r;
            Op[(((size_t)ks * 2 + bb) * CD + cch) * ND + q0 + lr] = (f16)oacc[ct][r];
        }
    if (lr == 0) {
#pragma unroll
        for (int r = 0; r < 4; ++r) {
            int n = q0 + lg * 4 + r;
            ml[((ks * 2 + bb) * 2 + 0) * ND + n] = row_m[r];
            ml[((ks * 2 + bb) * 2 + 1) * ND + n] = row_l[r];
        }
    }
}

// ============================================================================
// Kernel 2b: combine split-K partials -> Hb[b][c][n] f16
// ============================================================================
__global__ __launch_bounds__(256)
void k_comb(const f16* __restrict__ Op, const float* __restrict__ ml,
            f16* __restrict__ Hb)
{
    const int t  = threadIdx.x;
    const int tn = t & 63;
    const int cg = t >> 6;
    const int n  = blockIdx.x * 64 + tn;
    const int b  = blockIdx.y;

    float m[KS], lv[KS];
#pragma unroll
    for (int ks = 0; ks < KS; ++ks) {
        m[ks]  = ml[((ks * 2 + b) * 2 + 0) * ND + n];
        lv[ks] = ml[((ks * 2 + b) * 2 + 1) * ND + n];
    }
    float M = fmaxf(fmaxf(m[0], m[1]), fmaxf(m[2], m[3]));
    float wgt[KS];
    float L = 0.f;
#pragma unroll
    for (int ks = 0; ks < KS; ++ks) { wgt[ks] = __expf(m[ks] - M); L += wgt[ks] * lv[ks]; }
    float inv = 1.0f / L;

#pragma unroll 4
    for (int i = 0; i < 64; ++i) {
        int c = cg * 64 + i;
        float acc = 0.f;
#pragma unroll
        for (int ks = 0; ks < KS; ++ks)
            acc += wgt[ks] * (float)Op[(((size_t)ks * 2 + b) * CD + c) * ND + n];
        Hb[((size_t)b * CD + c) * ND + n] = (f16)(acc * inv);
    }
}

// ============================================================================
// Kernel 3: output projection + residual.  Y = Wo@H + bo + x  (f32 out)
// ============================================================================
__global__ __launch_bounds__(256)
void k_proj_o(const f16* __restrict__ Hb, const float* __restrict__ Wo,
              const float* __restrict__ bo, const float* __restrict__ x,
              float* __restrict__ Y)
{
    __shared__ f16 As[64][40];
    __shared__ f16 Bs[64][40];

    const int t  = threadIdx.x;
    const int n0 = blockIdx.x * 64;
    const int o0 = blockIdx.y * 64;
    const int bb = blockIdx.z;

    const int w  = t >> 6;
    const int l  = t & 63;
    const int lr = l & 15;
    const int lg = l >> 4;
    const int wo = (w >> 1) * 32;
    const int wn = (w & 1) * 32;

    const int sl = t & 63;
    const int k8 = (t >> 6) * 8;

    f32x4 acc[2][2] = {};

    for (int ck = 0; ck < CD; ck += 32) {
        __syncthreads();
        {
            const float* s = Wo + (size_t)(o0 + sl) * CD + ck + k8;
            f16x8 v;
#pragma unroll
            for (int u = 0; u < 8; ++u) v[u] = (f16)s[u];
            *(f16x8*)&As[sl][k8] = v;
        }
        {
            const f16* s = Hb + ((size_t)bb * CD + ck + k8) * ND + n0 + sl;
            f16x8 v;
#pragma unroll
            for (int u = 0; u < 8; ++u) v[u] = s[(size_t)u * ND];
            *(f16x8*)&Bs[sl][k8] = v;
        }
        __syncthreads();
        f16x8 a0 = *(const f16x8*)&As[wo + lr][lg * 8];
        f16x8 a1 = *(const f16x8*)&As[wo + 16 + lr][lg * 8];
        f16x8 b0 = *(const f16x8*)&Bs[wn + lr][lg * 8];
        f16x8 b1 = *(const f16x8*)&Bs[wn + 16 + lr][lg * 8];
        acc[0][0] = __builtin_amdgcn_mfma_f32_16x16x32_f16(a0, b0, acc[0][0], 0, 0, 0);
        acc[0][1] = __builtin_amdgcn_mfma_f32_16x16x32_f16(a0, b1, acc[0][1], 0, 0, 0);
        acc[1][0] = __builtin_amdgcn_mfma_f32_16x16x32_f16(a1, b0, acc[1][0], 0, 0, 0);
        acc[1][1] = __builtin_amdgcn_mfma_f32_16x16x32_f16(a1, b1, acc[1][1], 0, 0, 0);
    }

#pragma unroll
    for (int so = 0; so < 2; ++so)
#pragma unroll
        for (int r = 0; r < 4; ++r) {
            int orow  = wo + so * 16 + lg * 4 + r;
            float bv_ = bo[o0 + orow];
#pragma unroll
            for (int sn = 0; sn < 2; ++sn) {
                int ncol   = wn + sn * 16 + lr;
                size_t idx = ((size_t)bb * CD + o0 + orow) * ND + n0 + ncol;
                Y[idx] = acc[so][sn][r] + bv_ + x[idx];
            }
        }
}

// ============================================================================
// Kernel 4: per-(batch,group) mean/rstd
// ============================================================================
__global__ __launch_bounds__(256)
void k_stats(const float* __restrict__ Y, float* __restrict__ stats)
{
    const int g = blockIdx.x, b = blockIdx.y;
    const float* base = Y + ((size_t)b * CD + g * 8) * ND;
    float s = 0.f, s2 = 0.f;
    for (int i = threadIdx.x; i < (8 * ND) / 4; i += 256) {
        float4 v = ((const float4*)base)[i];
        s  += v.x + v.y + v.z + v.w;
        s2 += v.x * v.x + v.y * v.y + v.z * v.z + v.w * v.w;
    }
#pragma unroll
    for (int m = 1; m < 64; m <<= 1) {
        s  += __shfl_xor(s, m);
        s2 += __shfl_xor(s2, m);
    }
    __shared__ float red[8];
    if ((threadIdx.x & 63) == 0) {
        red[(threadIdx.x >> 6) * 2]     = s;
        red[(threadIdx.x >> 6) * 2 + 1] = s2;
    }
    __syncthreads();
    if (threadIdx.x == 0) {
        float S  = red[0] + red[2] + red[4] + red[6];
        float S2 = red[1] + red[3] + red[5] + red[7];
        float mean = S / 32768.f;
        float var  = S2 / 32768.f - mean * mean;
        stats[(b * GD + g) * 2]     = mean;
        stats[(b * GD + g) * 2 + 1] = rsqrtf(var + 1e-5f);
    }
}

// ============================================================================
// Kernel 5: normalize + affine + SiLU, f32 out
// ============================================================================
__global__ __launch_bounds__(256)
void k_norm_silu(const float* __restrict__ Y, const float* __restrict__ stats,
                 const float* __restrict__ gamma, const float* __restrict__ beta,
                 float* __restrict__ out)
{
    size_t i4 = (size_t)blockIdx.x * 256 + threadIdx.x;
    int c = (int)((i4 / (ND / 4)) % CD);
    int b = (int)(i4 / ((size_t)CD * (ND / 4)));
    float mean = stats[(b * GD + c / 8) * 2];
    float rstd = stats[(b * GD + c / 8) * 2 + 1];
    float ga = gamma[c], be = beta[c];
    float4 v = ((const float4*)Y)[i4];
    float in[4] = { v.x, v.y, v.z, v.w };
    float ob[4];
#pragma unroll
    for (int u = 0; u < 4; ++u) {
        float yn = (in[u] - mean) * rstd * ga + be;
        float sg = 1.0f / (1.0f + __expf(-yn));
        ob[u] = yn * sg;
    }
    *(float4*)(out + i4 * 4) = *(float4*)ob;
}

// ============================================================================
extern "C" void kernel_launch(void* const* d_in, const int* in_sizes, int n_in,
                              void* d_out, int out_size, void* d_ws, size_t ws_size,
                              hipStream_t stream)
{
    const float* x     = (const float*)d_in[0];
    const float* Wq    = (const float*)d_in[1];
    const float* bq    = (const float*)d_in[2];
    const float* Wk    = (const float*)d_in[3];
    const float* bk    = (const float*)d_in[4];
    const float* Wv    = (const float*)d_in[5];
    const float* bv    = (const float*)d_in[6];
    const float* Wo    = (const float*)d_in[7];
    const float* bo    = (const float*)d_in[8];
    const float* gamma = (const float*)d_in[9];
    const float* beta  = (const float*)d_in[10];

    char* ws = (char*)d_ws;
    f16*   Qt    = (f16*)(ws);                       //  0..4 MiB   [B][N][C]
    f16*   Kt    = (f16*)(ws + (4u << 20));          //  4..8 MiB   [B][N][C]
    f16*   Vb    = (f16*)(ws + (8u << 20));          //  8..12 MiB  [B][C][N]
    f16*   Hb    = (f16*)(ws + (12u << 20));         // 12..16 MiB  [B][C][N]
    f16*   Op    = (f16*)(ws + (16u << 20));         // 16..32 MiB  [KS][B][C][N]
    float* ml    = (float*)(ws + (32u << 20));       // 32..32.5 MiB [KS][B][2][N]
    float* Y     = (float*)(ws + (16u << 20));       // reuses Op region after combine
    float* stats = (float*)(ws + (33u << 20));       // 512 B

    k_proj_qkv<<<dim3(64, 4, 6), 256, 0, stream>>>(x, Wq, bq, Wk, bk, Wv, bv, Qt, Kt, Vb);
    k_attn<<<dim3(32, KS, 2), 512, 0, stream>>>(Qt, Kt, Vb, Op, ml);
    k_comb<<<dim3(64, 2), 256, 0, stream>>>(Op, ml, Hb);
    k_proj_o<<<dim3(64, 4, 2), 256, 0, stream>>>(Hb, Wo, bo, x, Y);
    k_stats<<<dim3(32, 2), 256, 0, stream>>>(Y, stats);
    k_norm_silu<<<2048, 256, 0, stream>>>(Y, stats, gamma, beta, (float*)d_out);
}

// Round 5
// 121.251 us; speedup vs baseline: 2.8774x; 1.0413x over previous
//
#include <hip/hip_runtime.h>
#include <hip/hip_bf16.h>

typedef _Float16 f16;
typedef __attribute__((ext_vector_type(4))) _Float16 f16x4;
typedef __attribute__((ext_vector_type(8))) _Float16 f16x8;
typedef __attribute__((ext_vector_type(4))) float f32x4;

#define CD 256
#define ND 4096
#define GD 32
#define KVB 32          // keys per iteration

// async global->LDS, 16B per lane, lds dest must be wave-uniform base
__device__ __forceinline__ void gl_lds16(const f16* g, f16* l) {
    __builtin_amdgcn_global_load_lds(
        (const __attribute__((address_space(1))) unsigned int*)g,
        (__attribute__((address_space(3))) unsigned int*)l,
        16, 0, 0);
}

// ============================================================================
// Kernel 1: QKV projection.  q[b,o,n] = sum_c W[o,c] x[b,c,n] + bias[o]
// Q,K written TRANSPOSED [b][n][c] f16; V natural [b][c][n] f16.
// ============================================================================
__global__ __launch_bounds__(256)
void k_proj_qkv(const float* __restrict__ x,
                const float* __restrict__ Wq, const float* __restrict__ bq,
                const float* __restrict__ Wk, const float* __restrict__ bk,
                const float* __restrict__ Wv, const float* __restrict__ bv,
                f16* __restrict__ Qt, f16* __restrict__ Kt, f16* __restrict__ Vb)
{
    __shared__ f16 As[64][40];
    __shared__ f16 Bs[64][40];
    __shared__ f16 Ts[64][72];

    const int t  = threadIdx.x;
    const int n0 = blockIdx.x * 64;
    const int o0 = blockIdx.y * 64;
    const int p  = blockIdx.z % 3;
    const int bb = blockIdx.z / 3;

    const float* W    = (p == 0) ? Wq : (p == 1) ? Wk : Wv;
    const float* bias = (p == 0) ? bq : (p == 1) ? bk : bv;

    const int w  = t >> 6;
    const int l  = t & 63;
    const int lr = l & 15;
    const int lg = l >> 4;
    const int wo = (w >> 1) * 32;
    const int wn = (w & 1) * 32;

    const int sl = t & 63;
    const int k8 = (t >> 6) * 8;

    f32x4 acc[2][2] = {};

    for (int ck = 0; ck < CD; ck += 32) {
        __syncthreads();
        {
            const float* s = W + (size_t)(o0 + sl) * CD + ck + k8;
            f16x8 v;
#pragma unroll
            for (int u = 0; u < 8; ++u) v[u] = (f16)s[u];
            *(f16x8*)&As[sl][k8] = v;
        }
        {
            const float* s = x + ((size_t)bb * CD + ck + k8) * ND + n0 + sl;
            f16x8 v;
#pragma unroll
            for (int u = 0; u < 8; ++u) v[u] = (f16)s[(size_t)u * ND];
            *(f16x8*)&Bs[sl][k8] = v;
        }
        __syncthreads();
        f16x8 a0 = *(const f16x8*)&As[wo + lr][lg * 8];
        f16x8 a1 = *(const f16x8*)&As[wo + 16 + lr][lg * 8];
        f16x8 b0 = *(const f16x8*)&Bs[wn + lr][lg * 8];
        f16x8 b1 = *(const f16x8*)&Bs[wn + 16 + lr][lg * 8];
        acc[0][0] = __builtin_amdgcn_mfma_f32_16x16x32_f16(a0, b0, acc[0][0], 0, 0, 0);
        acc[0][1] = __builtin_amdgcn_mfma_f32_16x16x32_f16(a0, b1, acc[0][1], 0, 0, 0);
        acc[1][0] = __builtin_amdgcn_mfma_f32_16x16x32_f16(a1, b0, acc[1][0], 0, 0, 0);
        acc[1][1] = __builtin_amdgcn_mfma_f32_16x16x32_f16(a1, b1, acc[1][1], 0, 0, 0);
    }

    if (p < 2) {
        __syncthreads();
#pragma unroll
        for (int so = 0; so < 2; ++so)
#pragma unroll
            for (int r = 0; r < 4; ++r) {
                int orow  = wo + so * 16 + lg * 4 + r;
                float bv_ = bias[o0 + orow];
#pragma unroll
                for (int sn = 0; sn < 2; ++sn)
                    Ts[orow][wn + sn * 16 + lr] = (f16)(acc[so][sn][r] + bv_);
            }
        __syncthreads();
        f16* dst = (p == 0) ? Qt : Kt;
        int n  = t >> 2;
        int o8 = (t & 3) * 16;
        f16 tmp[16];
#pragma unroll
        for (int u = 0; u < 16; ++u) tmp[u] = Ts[o8 + u][n];
        f16* g = dst + ((size_t)bb * ND + n0 + n) * CD + o0 + o8;
        *(f16x8*)g       = *(f16x8*)&tmp[0];
        *(f16x8*)(g + 8) = *(f16x8*)&tmp[8];
    } else {
#pragma unroll
        for (int so = 0; so < 2; ++so)
#pragma unroll
            for (int r = 0; r < 4; ++r) {
                int orow  = wo + so * 16 + lg * 4 + r;
                float bv_ = bias[o0 + orow];
#pragma unroll
                for (int sn = 0; sn < 2; ++sn) {
                    int ncol = wn + sn * 16 + lr;
                    Vb[((size_t)bb * CD + o0 + orow) * ND + n0 + ncol] =
                        (f16)(acc[so][sn][r] + bv_);
                }
            }
    }
}

// ============================================================================
// Kernel 2: flash attention, split-K (template KSN).
// 4 waves x 32 queries (QBLK=128).  KVB=32 keys/iter, double-buffered LDS,
// 2 blocks/CU.  SWAPPED QK^T: S = mfma(A=K, B=Q) so each lane owns a full
// score column for one q -> lane-local softmax (2 shfls), per-lane rescale.
// P goes through a small padded LDS buffer (b64 writes, b128 read) into the
// PV B-fragment.  Each K/V fragment read feeds 2 MFMAs (2 q-subgroups).
// ============================================================================
template<int KSN>
__global__ __launch_bounds__(256, 2)
void k_attn(const f16* __restrict__ Qt, const f16* __restrict__ Kt,
            const f16* __restrict__ Vb, f16* __restrict__ Op,
            float* __restrict__ ml)
{
    __shared__ f16 Ks[2][32 * 256];   // [buf][row][chunk16B ^ (row&7)]  2x16 KB
    __shared__ f16 Vs[2][256 * 32];   // [buf][c][chunk16B ^ ((c>>1)&3)] 2x16 KB
    __shared__ f16 Pl[4][32][40];     // per-wave P [q_local][m], pad->free banks

    const int t  = threadIdx.x;
    const int w  = t >> 6;           // 0..3
    const int l  = t & 63;
    const int lr = l & 15;
    const int lg = l >> 4;
    const int ks = blockIdx.y;
    const int bb = blockIdx.z;
    const int q0 = blockIdx.x * 128 + w * 32;

    // Q fragments in registers: 2 q-subgroups x 8 k-chunks
    f16x8 qf[2][8];
#pragma unroll
    for (int qs = 0; qs < 2; ++qs)
#pragma unroll
        for (int kc = 0; kc < 8; ++kc)
            qf[qs][kc] = *(const f16x8*)(Qt + ((size_t)bb * ND + q0 + qs * 16 + lr) * CD + kc * 32 + lg * 8);

    f32x4 oacc[2][16] = {};
    float row_m[2] = { -3.0e38f, -3.0e38f };
    float row_l[2] = { 0.f, 0.f };

    const int kv0 = ks * (ND / KSN);
    const f16* ktb = Kt + (size_t)bb * ND * CD;
    const f16* vbb = Vb + (size_t)bb * CD * ND;

    // per-lane loop-invariant staging offsets (elements)
    int koff[4], voff[4];
#pragma unroll
    for (int j = 0; j < 4; ++j) {
        int v   = (w * 4 + j) * 64 + l;
        int row = v >> 5;
        int ch  = (v & 31) ^ (row & 7);
        koff[j] = row * CD + ch * 8;
        int c   = v >> 2;
        int u   = (v & 3) ^ ((c >> 1) & 3);
        voff[j] = c * ND + u * 8;
    }

    auto stage = [&](int m0, int bi) {
#pragma unroll
        for (int j = 0; j < 4; ++j)
            gl_lds16(ktb + (size_t)m0 * CD + koff[j], &Ks[bi][(w * 4 + j) * 512]);
#pragma unroll
        for (int j = 0; j < 4; ++j)
            gl_lds16(vbb + m0 + voff[j], &Vs[bi][(w * 4 + j) * 512]);
    };

    stage(kv0, 0);
    __syncthreads();    // drains vmcnt; tile 0 resident

    const int NIT = (ND / KSN) / KVB;
    for (int it = 0; it < NIT; ++it) {
        const int bi = it & 1;
        if (it + 1 < NIT) stage(kv0 + (it + 1) * KVB, bi ^ 1);

        // ---- scores S[m][q]: 2 m-subtiles x 2 q-subgroups ----
        f32x4 s[2][2] = {};
        __builtin_amdgcn_s_setprio(1);
#pragma unroll
        for (int kc = 0; kc < 8; ++kc) {
            int chs = ((kc * 4 + lg) ^ (lr & 7)) * 8;
            f16x8 k0 = *(const f16x8*)&Ks[bi][(lr) * 256 + chs];
            f16x8 k1 = *(const f16x8*)&Ks[bi][(16 + lr) * 256 + chs];
            s[0][0] = __builtin_amdgcn_mfma_f32_16x16x32_f16(k0, qf[0][kc], s[0][0], 0, 0, 0);
            s[1][0] = __builtin_amdgcn_mfma_f32_16x16x32_f16(k1, qf[0][kc], s[1][0], 0, 0, 0);
            s[0][1] = __builtin_amdgcn_mfma_f32_16x16x32_f16(k0, qf[1][kc], s[0][1], 0, 0, 0);
            s[1][1] = __builtin_amdgcn_mfma_f32_16x16x32_f16(k1, qf[1][kc], s[1][1], 0, 0, 0);
        }
        __builtin_amdgcn_s_setprio(0);

        // ---- lane-local online softmax per q-subgroup ----
        // lane (lr,lg) holds S[m = sub*16 + lg*4 + r][q = lr]
#pragma unroll
        for (int qs = 0; qs < 2; ++qs) {
            float pm = fmaxf(
                fmaxf(fmaxf(s[0][qs][0], s[0][qs][1]), fmaxf(s[0][qs][2], s[0][qs][3])),
                fmaxf(fmaxf(s[1][qs][0], s[1][qs][1]), fmaxf(s[1][qs][2], s[1][qs][3])));
            pm = fmaxf(pm, __shfl_xor(pm, 16));
            pm = fmaxf(pm, __shfl_xor(pm, 32));
            float nm = fmaxf(row_m[qs], pm);
            float sc = __expf(row_m[qs] - nm);
            float p0 = __expf(s[0][qs][0] - nm);
            float p1 = __expf(s[0][qs][1] - nm);
            float p2 = __expf(s[0][qs][2] - nm);
            float p3 = __expf(s[0][qs][3] - nm);
            float p4 = __expf(s[1][qs][0] - nm);
            float p5 = __expf(s[1][qs][1] - nm);
            float p6 = __expf(s[1][qs][2] - nm);
            float p7 = __expf(s[1][qs][3] - nm);
            float ps = ((p0 + p1) + (p2 + p3)) + ((p4 + p5) + (p6 + p7));
            ps += __shfl_xor(ps, 16);
            ps += __shfl_xor(ps, 32);
            bool chg = nm > row_m[qs];
            row_l[qs] = row_l[qs] * sc + ps;
            row_m[qs] = nm;
            if (__any(chg)) {   // skip exact-1 rescale when max unchanged
#pragma unroll
                for (int ct = 0; ct < 16; ++ct) {
                    oacc[qs][ct][0] *= sc; oacc[qs][ct][1] *= sc;
                    oacc[qs][ct][2] *= sc; oacc[qs][ct][3] *= sc;
                }
            }
            f16x4 pk0 = { (f16)p0, (f16)p1, (f16)p2, (f16)p3 };
            f16x4 pk1 = { (f16)p4, (f16)p5, (f16)p6, (f16)p7 };
            *(f16x4*)&Pl[w][qs * 16 + lr][lg * 4]      = pk0;
            *(f16x4*)&Pl[w][qs * 16 + lr][16 + lg * 4] = pk1;
        }

        // ---- PV: O[c][q] += V[c][m] * P[m][q] ----
        f16x8 pf0 = *(const f16x8*)&Pl[w][lr][lg * 8];
        f16x8 pf1 = *(const f16x8*)&Pl[w][16 + lr][lg * 8];
        __builtin_amdgcn_s_setprio(1);
#pragma unroll
        for (int ct = 0; ct < 16; ++ct) {
            f16x8 vf = *(const f16x8*)&Vs[bi][(ct * 16 + lr) * 32 + ((lg ^ ((lr >> 1) & 3))) * 8];
            oacc[0][ct] = __builtin_amdgcn_mfma_f32_16x16x32_f16(vf, pf0, oacc[0][ct], 0, 0, 0);
            oacc[1][ct] = __builtin_amdgcn_mfma_f32_16x16x32_f16(vf, pf1, oacc[1][ct], 0, 0, 0);
        }
        __builtin_amdgcn_s_setprio(0);
        __syncthreads();   // drains stage(it+1); frees buffers for next iter
    }

    // ---- write unnormalized partial + (m,l) ----
#pragma unroll
    for (int qs = 0; qs < 2; ++qs)
#pragma unroll
        for (int ct = 0; ct < 16; ++ct)
#pragma unroll
            for (int r = 0; r < 4; ++r) {
                int cch = ct * 16 + lg * 4 + r;
                Op[(((size_t)ks * 2 + bb) * CD + cch) * ND + q0 + qs * 16 + lr] =
                    (f16)oacc[qs][ct][r];
            }
    if (lg == 0) {
#pragma unroll
        for (int qs = 0; qs < 2; ++qs) {
            int n = q0 + qs * 16 + lr;
            ml[((ks * 2 + bb) * 2 + 0) * ND + n] = row_m[qs];
            ml[((ks * 2 + bb) * 2 + 1) * ND + n] = row_l[qs];
        }
    }
}

// ============================================================================
// Kernel 2b-i: per-n combine weights  wq[ks][b][n] = exp(m-M)/L
// ============================================================================
template<int KSN>
__global__ __launch_bounds__(256)
void k_ml(const float* __restrict__ ml, float* __restrict__ wq)
{
    int i = blockIdx.x * 256 + threadIdx.x;   // i over B*ND
    int b = i / ND, n = i % ND;
    float m[KSN], lv[KSN];
#pragma unroll
    for (int ks = 0; ks < KSN; ++ks) {
        m[ks]  = ml[((ks * 2 + b) * 2 + 0) * ND + n];
        lv[ks] = ml[((ks * 2 + b) * 2 + 1) * ND + n];
    }
    float M = m[0];
#pragma unroll
    for (int ks = 1; ks < KSN; ++ks) M = fmaxf(M, m[ks]);
    float wgt[KSN], L = 0.f;
#pragma unroll
    for (int ks = 0; ks < KSN; ++ks) { wgt[ks] = __expf(m[ks] - M); L += wgt[ks] * lv[ks]; }
    float inv = 1.0f / L;
#pragma unroll
    for (int ks = 0; ks < KSN; ++ks)
        wq[(ks * 2 + b) * ND + n] = wgt[ks] * inv;
}

// ============================================================================
// Kernel 2b-ii: combine split-K partials -> Hb[b][c][n] f16 (vectorized)
// ============================================================================
template<int KSN>
__global__ __launch_bounds__(256)
void k_comb(const f16* __restrict__ Op, const float* __restrict__ wq,
            f16* __restrict__ Hb)
{
    size_t i = (size_t)blockIdx.x * 256 + threadIdx.x;   // one f16x8 each
    int n0 = (int)(i % (ND / 8)) * 8;
    int c  = (int)((i / (ND / 8)) % CD);
    int b  = (int)(i / ((size_t)CD * (ND / 8)));

    float acc[8] = {};
#pragma unroll
    for (int ks = 0; ks < KSN; ++ks) {
        f16x8 o = *(const f16x8*)(Op + (((size_t)ks * 2 + b) * CD + c) * ND + n0);
        const float* wp = wq + (ks * 2 + b) * ND + n0;
        float4 w0 = *(const float4*)wp;
        float4 w1 = *(const float4*)(wp + 4);
        acc[0] += w0.x * (float)o[0]; acc[1] += w0.y * (float)o[1];
        acc[2] += w0.z * (float)o[2]; acc[3] += w0.w * (float)o[3];
        acc[4] += w1.x * (float)o[4]; acc[5] += w1.y * (float)o[5];
        acc[6] += w1.z * (float)o[6]; acc[7] += w1.w * (float)o[7];
    }
    f16x8 h;
#pragma unroll
    for (int u = 0; u < 8; ++u) h[u] = (f16)acc[u];
    *(f16x8*)(Hb + ((size_t)b * CD + c) * ND + n0) = h;
}

// ============================================================================
// Kernel 3: output projection + residual.  Y = Wo@H + bo + x  (f32 out)
// ============================================================================
__global__ __launch_bounds__(256)
void k_proj_o(const f16* __restrict__ Hb, const float* __restrict__ Wo,
              const float* __restrict__ bo, const float* __restrict__ x,
              float* __restrict__ Y)
{
    __shared__ f16 As[64][40];
    __shared__ f16 Bs[64][40];

    const int t  = threadIdx.x;
    const int n0 = blockIdx.x * 64;
    const int o0 = blockIdx.y * 64;
    const int bb = blockIdx.z;

    const int w  = t >> 6;
    const int l  = t & 63;
    const int lr = l & 15;
    const int lg = l >> 4;
    const int wo = (w >> 1) * 32;
    const int wn = (w & 1) * 32;

    const int sl = t & 63;
    const int k8 = (t >> 6) * 8;

    f32x4 acc[2][2] = {};

    for (int ck = 0; ck < CD; ck += 32) {
        __syncthreads();
        {
            const float* s = Wo + (size_t)(o0 + sl) * CD + ck + k8;
            f16x8 v;
#pragma unroll
            for (int u = 0; u < 8; ++u) v[u] = (f16)s[u];
            *(f16x8*)&As[sl][k8] = v;
        }
        {
            const f16* s = Hb + ((size_t)bb * CD + ck + k8) * ND + n0 + sl;
            f16x8 v;
#pragma unroll
            for (int u = 0; u < 8; ++u) v[u] = s[(size_t)u * ND];
            *(f16x8*)&Bs[sl][k8] = v;
        }
        __syncthreads();
        f16x8 a0 = *(const f16x8*)&As[wo + lr][lg * 8];
        f16x8 a1 = *(const f16x8*)&As[wo + 16 + lr][lg * 8];
        f16x8 b0 = *(const f16x8*)&Bs[wn + lr][lg * 8];
        f16x8 b1 = *(const f16x8*)&Bs[wn + 16 + lr][lg * 8];
        acc[0][0] = __builtin_amdgcn_mfma_f32_16x16x32_f16(a0, b0, acc[0][0], 0, 0, 0);
        acc[0][1] = __builtin_amdgcn_mfma_f32_16x16x32_f16(a0, b1, acc[0][1], 0, 0, 0);
        acc[1][0] = __builtin_amdgcn_mfma_f32_16x16x32_f16(a1, b0, acc[1][0], 0, 0, 0);
        acc[1][1] = __builtin_amdgcn_mfma_f32_16x16x32_f16(a1, b1, acc[1][1], 0, 0, 0);
    }

#pragma unroll
    for (int so = 0; so < 2; ++so)
#pragma unroll
        for (int r = 0; r < 4; ++r) {
            int orow  = wo + so * 16 + lg * 4 + r;
            float bv_ = bo[o0 + orow];
#pragma unroll
            for (int sn = 0; sn < 2; ++sn) {
                int ncol   = wn + sn * 16 + lr;
                size_t idx = ((size_t)bb * CD + o0 + orow) * ND + n0 + ncol;
                Y[idx] = acc[so][sn][r] + bv_ + x[idx];
            }
        }
}

// ============================================================================
// Kernel 4: per-(batch,group) mean/rstd
// ============================================================================
__global__ __launch_bounds__(256)
void k_stats(const float* __restrict__ Y, float* __restrict__ stats)
{
    const int g = blockIdx.x, b = blockIdx.y;
    const float* base = Y + ((size_t)b * CD + g * 8) * ND;
    float s = 0.f, s2 = 0.f;
    for (int i = threadIdx.x; i < (8 * ND) / 4; i += 256) {
        float4 v = ((const float4*)base)[i];
        s  += v.x + v.y + v.z + v.w;
        s2 += v.x * v.x + v.y * v.y + v.z * v.z + v.w * v.w;
    }
#pragma unroll
    for (int m = 1; m < 64; m <<= 1) {
        s  += __shfl_xor(s, m);
        s2 += __shfl_xor(s2, m);
    }
    __shared__ float red[8];
    if ((threadIdx.x & 63) == 0) {
        red[(threadIdx.x >> 6) * 2]     = s;
        red[(threadIdx.x >> 6) * 2 + 1] = s2;
    }
    __syncthreads();
    if (threadIdx.x == 0) {
        float S  = red[0] + red[2] + red[4] + red[6];
        float S2 = red[1] + red[3] + red[5] + red[7];
        float mean = S / 32768.f;
        float var  = S2 / 32768.f - mean * mean;
        stats[(b * GD + g) * 2]     = mean;
        stats[(b * GD + g) * 2 + 1] = rsqrtf(var + 1e-5f);
    }
}

// ============================================================================
// Kernel 5: normalize + affine + SiLU, f32 out
// ============================================================================
__global__ __launch_bounds__(256)
void k_norm_silu(const float* __restrict__ Y, const float* __restrict__ stats,
                 const float* __restrict__ gamma, const float* __restrict__ beta,
                 float* __restrict__ out)
{
    size_t i4 = (size_t)blockIdx.x * 256 + threadIdx.x;
    int c = (int)((i4 / (ND / 4)) % CD);
    int b = (int)(i4 / ((size_t)CD * (ND / 4)));
    float mean = stats[(b * GD + c / 8) * 2];
    float rstd = stats[(b * GD + c / 8) * 2 + 1];
    float ga = gamma[c], be = beta[c];
    float4 v = ((const float4*)Y)[i4];
    float in[4] = { v.x, v.y, v.z, v.w };
    float ob[4];
#pragma unroll
    for (int u = 0; u < 4; ++u) {
        float yn = (in[u] - mean) * rstd * ga + be;
        float sg = 1.0f / (1.0f + __expf(-yn));
        ob[u] = yn * sg;
    }
    *(float4*)(out + i4 * 4) = *(float4*)ob;
}

// ============================================================================
extern "C" void kernel_launch(void* const* d_in, const int* in_sizes, int n_in,
                              void* d_out, int out_size, void* d_ws, size_t ws_size,
                              hipStream_t stream)
{
    const float* x     = (const float*)d_in[0];
    const float* Wq    = (const float*)d_in[1];
    const float* bq    = (const float*)d_in[2];
    const float* Wk    = (const float*)d_in[3];
    const float* bk    = (const float*)d_in[4];
    const float* Wv    = (const float*)d_in[5];
    const float* bv    = (const float*)d_in[6];
    const float* Wo    = (const float*)d_in[7];
    const float* bo    = (const float*)d_in[8];
    const float* gamma = (const float*)d_in[9];
    const float* beta  = (const float*)d_in[10];

    char* ws = (char*)d_ws;
    f16* Qt = (f16*)(ws);                    //  0..4 MiB   [B][N][C]
    f16* Kt = (f16*)(ws + (4u << 20));       //  4..8 MiB   [B][N][C]
    f16* Vb = (f16*)(ws + (8u << 20));       //  8..12 MiB  [B][C][N]
    f16* Hb = (f16*)(ws + (12u << 20));      // 12..16 MiB  [B][C][N]
    f16* Op = (f16*)(ws + (16u << 20));      // 16.. MiB    [KSN][B][C][N]
    float* Y = (float*)(ws + (16u << 20));   // reuses Op region after combine

    const bool big = ws_size >= (50ull << 20);

    k_proj_qkv<<<dim3(64, 4, 6), 256, 0, stream>>>(x, Wq, bq, Wk, bk, Wv, bv, Qt, Kt, Vb);

    if (big) {
        constexpr int KSN = 8;
        float* ml    = (float*)(ws + (48u << 20));            // 512 KB
        float* wq    = (float*)(ws + (48u << 20) + (768u << 10)); // 256 KB
        float* stats = (float*)(ws + (49u << 20) + (512u << 10));
        k_attn<KSN><<<dim3(32, KSN, 2), 256, 0, stream>>>(Qt, Kt, Vb, Op, ml);
        k_ml<KSN><<<dim3((2 * ND) / 256), 256, 0, stream>>>(ml, wq);
        k_comb<KSN><<<dim3((2 * CD * ND / 8) / 256), 256, 0, stream>>>(Op, wq, Hb);
        k_proj_o<<<dim3(64, 4, 2), 256, 0, stream>>>(Hb, Wo, bo, x, Y);
        k_stats<<<dim3(32, 2), 256, 0, stream>>>(Y, stats);
        k_norm_silu<<<2048, 256, 0, stream>>>(Y, stats, gamma, beta, (float*)d_out);
    } else {
        constexpr int KSN = 4;
        float* ml    = (float*)(ws + (32u << 20));            // 256 KB
        float* wq    = (float*)(ws + (32u << 20) + (512u << 10)); // 128 KB
        float* stats = (float*)(ws + (33u << 20));
        k_attn<KSN><<<dim3(32, KSN, 2), 256, 0, stream>>>(Qt, Kt, Vb, Op, ml);
        k_ml<KSN><<<dim3((2 * ND) / 256), 256, 0, stream>>>(ml, wq);
        k_comb<KSN><<<dim3((2 * CD * ND / 8) / 256), 256, 0, stream>>>(Op, wq, Hb);
        k_proj_o<<<dim3(64, 4, 2), 256, 0, stream>>>(Hb, Wo, bo, x, Y);
        k_stats<<<dim3(32, 2), 256, 0, stream>>>(Y, stats);
        k_norm_silu<<<2048, 256, 0, stream>>>(Y, stats, gamma, beta, (float*)d_out);
    }
}